// Round 1
// baseline (302.959 us; speedup 1.0000x reference)
//
#include <hip/hip_runtime.h>
#include <hip/hip_bf16.h>
#include <stdint.h>

// ---------------------------------------------------------------------------
// JointEmbeddingClassifier on MI355X (gfx950)
//   P = x@Wp+bp ; S = x@Ws+bs ; parent = P@Wc+bc
//   child0 = einsum(S, cw0[y])+cb0[y] ; child1 = einsum(S, cw1[y])+cb1[y]
// Strategy: bf16 MFMA for all matmul work (thresholds are bf16-floor).
//   gemm1: [4096,4096]x[4096,2048] fused Wp|Ws  (dominant, 68.7 GFLOP)
//   gemm2: dense all-class child+parent logits [4096,3200], K=1024
//   gather: per-sample slice of dense child logits
// ---------------------------------------------------------------------------

typedef __attribute__((ext_vector_type(4))) float  floatx4;
typedef __attribute__((ext_vector_type(8))) short  shortx8;
typedef __attribute__((ext_vector_type(4))) short  shortx4;
typedef __attribute__((ext_vector_type(8))) __bf16 bf16x8;

static __device__ __forceinline__ ushort f32_to_bf16_rne(float f) {
  uint32_t u = __builtin_bit_cast(uint32_t, f);
  u += 0x7FFFu + ((u >> 16) & 1u);      // round-nearest-even (no NaN inputs here)
  return (ushort)(u >> 16);
}
static __device__ __forceinline__ float bf16u_to_f32(ushort h) {
  uint32_t u = ((uint32_t)h) << 16;
  return __builtin_bit_cast(float, u);
}

// async global->LDS, 16B per lane. LDS dest is wave-uniform base + lane*16.
static __device__ __forceinline__ void async_copy16(const void* g, void* lds) {
  __builtin_amdgcn_global_load_lds(
      (__attribute__((address_space(1))) void*)(uintptr_t)g,
      (__attribute__((address_space(3))) void*)(uintptr_t)lds,
      16, 0, 0);
}

#define BM 128
#define BN 128
#define BK 64

// C[mTile*128.., nTile*128..] += A[m,:K] . B[n,:K]^T   (both operands [rows][K] bf16)
// LDS tiles are XOR-swizzled by row (physical 16B-chunk = logical ^ (row&7)) so the
// MFMA fragment ds_read_b128s are bank-conflict-free; swizzle is applied by permuting
// the GLOBAL chunk each lane fetches (LDS dest order is fixed by global_load_lds).
static __device__ __forceinline__ void gemm_core_128(
    const ushort* __restrict__ A, const ushort* __restrict__ B,
    int lda, int ldb, int K, int mTile, int nTile,
    ushort* lA, ushort* lB, floatx4 acc[4][4])
{
  const int t    = threadIdx.x;
  const int w    = t >> 6;      // wave 0..3 (2x2 grid of 64x64 sub-tiles)
  const int lane = t & 63;
  const int wr   = w >> 1;
  const int wc   = w & 1;
  const int r16  = lane & 15;
  const int quad = lane >> 4;
  const int sr   = lane >> 3;   // staging: row within 8-row group
  const int sc   = lane & 7;    // staging: 16B chunk slot

  const ushort* Abase = A + (size_t)(mTile * BM) * lda;
  const ushort* Bbase = B + (size_t)(nTile * BN) * ldb;

  for (int k0 = 0; k0 < K; k0 += BK) {
    // stage A & B tiles: each wave covers rows 32w..32w+31, 1KB per call
    #pragma unroll
    for (int c2 = 0; c2 < 4; ++c2) {
      const int r  = 32 * w + 8 * c2 + sr;
      const int gc = sc ^ (r & 7);                       // swizzled global chunk
      async_copy16(Abase + (size_t)r * lda + k0 + gc * 8, lA + (32 * w + 8 * c2) * BK);
      async_copy16(Bbase + (size_t)r * ldb + k0 + gc * 8, lB + (32 * w + 8 * c2) * BK);
    }
    __syncthreads();   // compiler drains vmcnt before s_barrier

    #pragma unroll
    for (int ks = 0; ks < 2; ++ks) {
      bf16x8 af[4], bfv[4];
      const int pc = (((ks * 4) + quad) ^ (r16 & 7)) * 8;  // physical chunk offset (ushorts)
      #pragma unroll
      for (int mi = 0; mi < 4; ++mi) {
        const int row = wr * 64 + mi * 16 + r16;
        af[mi] = *reinterpret_cast<const bf16x8*>(lA + row * BK + pc);
      }
      #pragma unroll
      for (int ni = 0; ni < 4; ++ni) {
        const int row = wc * 64 + ni * 16 + r16;
        bfv[ni] = *reinterpret_cast<const bf16x8*>(lB + row * BK + pc);
      }
      #pragma unroll
      for (int mi = 0; mi < 4; ++mi)
        #pragma unroll
        for (int ni = 0; ni < 4; ++ni)
          acc[mi][ni] = __builtin_amdgcn_mfma_f32_16x16x32_bf16(
              af[mi], bfv[ni], acc[mi][ni], 0, 0, 0);
    }
    __syncthreads();
  }
}

// --- prep kernels -----------------------------------------------------------

// x f32 [4096*4096] -> bf16
__global__ __launch_bounds__(256) void k_cast_x(const float* __restrict__ x,
                                                ushort* __restrict__ xb)
{
  const size_t i = ((size_t)blockIdx.x * 256 + threadIdx.x) * 8;
  floatx4 a = *reinterpret_cast<const floatx4*>(x + i);
  floatx4 b = *reinterpret_cast<const floatx4*>(x + i + 4);
  shortx8 o;
  o[0] = (short)f32_to_bf16_rne(a[0]); o[1] = (short)f32_to_bf16_rne(a[1]);
  o[2] = (short)f32_to_bf16_rne(a[2]); o[3] = (short)f32_to_bf16_rne(a[3]);
  o[4] = (short)f32_to_bf16_rne(b[0]); o[5] = (short)f32_to_bf16_rne(b[1]);
  o[6] = (short)f32_to_bf16_rne(b[2]); o[7] = (short)f32_to_bf16_rne(b[3]);
  *reinterpret_cast<shortx8*>(xb + i) = o;
}

// Wp,Ws f32 [4096][1024] -> Bt1 bf16 [2048][4096] (row n = W^T col, K-contiguous)
__global__ __launch_bounds__(256) void k_transpose_w(const float* __restrict__ Wp,
                                                     const float* __restrict__ Ws,
                                                     ushort* __restrict__ Bt1)
{
  __shared__ __align__(16) ushort tile[64][72];   // +8 pad keeps 16B-aligned rows
  const float* W = blockIdx.z ? Ws : Wp;
  const int kt = blockIdx.x;   // 0..63 (k tile)
  const int nt = blockIdx.y;   // 0..15 (n tile)
  const int t  = threadIdx.x;
  const int r  = t >> 4;        // 0..15
  const int c  = (t & 15) * 4;  // 0..60
  #pragma unroll
  for (int i = 0; i < 4; ++i) {
    const int kk = r + i * 16;
    floatx4 v = *reinterpret_cast<const floatx4*>(
        W + (size_t)(kt * 64 + kk) * 1024 + nt * 64 + c);
    tile[c + 0][kk] = f32_to_bf16_rne(v[0]);
    tile[c + 1][kk] = f32_to_bf16_rne(v[1]);
    tile[c + 2][kk] = f32_to_bf16_rne(v[2]);
    tile[c + 3][kk] = f32_to_bf16_rne(v[3]);
  }
  __syncthreads();
  const int nl = t >> 3;  // 0..31
  const int ch = t & 7;
  #pragma unroll
  for (int i = 0; i < 2; ++i) {
    const int n = nl + i * 32;
    shortx8 v = *reinterpret_cast<const shortx8*>(&tile[n][ch * 8]);
    *reinterpret_cast<shortx8*>(
        Bt1 + (size_t)(blockIdx.z * 1024 + nt * 64 + n) * 4096 + kt * 64 + ch * 8) = v;
  }
}

// Bt2 bf16 [3200][1024]: rows 0..1023 cw0 flat, 1024..3071 cw1 flat,
// 3072..3103 Wc^T, 3104..3199 zeros. One block per row.
__global__ __launch_bounds__(256) void k_prep_bt2(const float* __restrict__ cw0,
                                                  const float* __restrict__ cw1,
                                                  const float* __restrict__ Wc,
                                                  ushort* __restrict__ Bt2)
{
  const int idx = (blockIdx.x * 256 + threadIdx.x) * 4;
  const int row = idx >> 10;
  const int k   = idx & 1023;
  float v0, v1, v2, v3;
  if (row < 1024) {
    floatx4 f = *reinterpret_cast<const floatx4*>(cw0 + idx);
    v0 = f[0]; v1 = f[1]; v2 = f[2]; v3 = f[3];
  } else if (row < 3072) {
    floatx4 f = *reinterpret_cast<const floatx4*>(cw1 + (size_t)(row - 1024) * 1024 + k);
    v0 = f[0]; v1 = f[1]; v2 = f[2]; v3 = f[3];
  } else if (row < 3104) {
    const int n = row - 3072;
    v0 = Wc[(k + 0) * 32 + n]; v1 = Wc[(k + 1) * 32 + n];
    v2 = Wc[(k + 2) * 32 + n]; v3 = Wc[(k + 3) * 32 + n];
  } else {
    v0 = v1 = v2 = v3 = 0.f;
  }
  shortx4 o;
  o[0] = (short)f32_to_bf16_rne(v0); o[1] = (short)f32_to_bf16_rne(v1);
  o[2] = (short)f32_to_bf16_rne(v2); o[3] = (short)f32_to_bf16_rne(v3);
  *reinterpret_cast<shortx4*>(Bt2 + idx) = o;
}

// --- main GEMMs -------------------------------------------------------------

// C[4096,2048] = xb . Bt1^T ; cols 0..1023 -> P (+bp), 1024..2047 -> S (+bs)
// writes f32 to d_out and bf16 copies to ws (Pb, Sb)
__global__ __launch_bounds__(256) void k_gemm1(
    const ushort* __restrict__ xb, const ushort* __restrict__ Bt1,
    const float* __restrict__ bp, const float* __restrict__ bs,
    float* __restrict__ outP, float* __restrict__ outS,
    ushort* __restrict__ Pb, ushort* __restrict__ Sb)
{
  __shared__ __align__(16) ushort lA[BM * BK];
  __shared__ __align__(16) ushort lB[BN * BK];
  floatx4 acc[4][4];
  const floatx4 z = {0.f, 0.f, 0.f, 0.f};
  #pragma unroll
  for (int i = 0; i < 4; ++i)
    #pragma unroll
    for (int j = 0; j < 4; ++j) acc[i][j] = z;

  gemm_core_128(xb, Bt1, 4096, 4096, 4096, blockIdx.x, blockIdx.y, lA, lB, acc);

  const int t = threadIdx.x, w = t >> 6, lane = t & 63;
  const int wr = w >> 1, wc = w & 1, r16 = lane & 15, quad = lane >> 4;
  const int sel = (blockIdx.y >= 8);
  const float* bias = sel ? bs : bp;
  float*  outF = sel ? outS : outP;
  ushort* outB = sel ? Sb : Pb;
  const int colbase = blockIdx.y * 128 - sel * 1024;
  #pragma unroll
  for (int mi = 0; mi < 4; ++mi) {
    #pragma unroll
    for (int ni = 0; ni < 4; ++ni) {
      const int n = colbase + wc * 64 + ni * 16 + r16;
      const float bv = bias[n];
      #pragma unroll
      for (int rg = 0; rg < 4; ++rg) {
        const int m = blockIdx.x * 128 + wr * 64 + mi * 16 + quad * 4 + rg;
        const float v = acc[mi][ni][rg] + bv;
        const size_t off = (size_t)m * 1024 + n;
        outF[off] = v;
        outB[off] = f32_to_bf16_rne(v);
      }
    }
  }
}

// D[4096,3200] = {Sb|Pb} . Bt2^T ; tiles 0..23 (cols 0..3071, A=Sb) -> dense2 bf16
// tile 24 (cols 3072..3103, A=Pb) -> parent_logits f32 (+bc), rest discarded
__global__ __launch_bounds__(256) void k_gemm2(
    const ushort* __restrict__ Sb, const ushort* __restrict__ Pb,
    const ushort* __restrict__ Bt2, const float* __restrict__ bc,
    ushort* __restrict__ dense2, float* __restrict__ outParent)
{
  __shared__ __align__(16) ushort lA[BM * BK];
  __shared__ __align__(16) ushort lB[BN * BK];
  floatx4 acc[4][4];
  const floatx4 z = {0.f, 0.f, 0.f, 0.f};
  #pragma unroll
  for (int i = 0; i < 4; ++i)
    #pragma unroll
    for (int j = 0; j < 4; ++j) acc[i][j] = z;

  const ushort* Ap = (blockIdx.y < 24) ? Sb : Pb;
  gemm_core_128(Ap, Bt2, 1024, 1024, 1024, blockIdx.x, blockIdx.y, lA, lB, acc);

  const int t = threadIdx.x, w = t >> 6, lane = t & 63;
  const int wr = w >> 1, wc = w & 1, r16 = lane & 15, quad = lane >> 4;
  if (blockIdx.y < 24) {
    const int nbase = blockIdx.y * 128;
    #pragma unroll
    for (int mi = 0; mi < 4; ++mi) {
      #pragma unroll
      for (int ni = 0; ni < 4; ++ni) {
        const int n = nbase + wc * 64 + ni * 16 + r16;
        #pragma unroll
        for (int rg = 0; rg < 4; ++rg) {
          const int m = blockIdx.x * 128 + wr * 64 + mi * 16 + quad * 4 + rg;
          dense2[(size_t)m * 3072 + n] = f32_to_bf16_rne(acc[mi][ni][rg]);
        }
      }
    }
  } else if (wc == 0) {
    #pragma unroll
    for (int mi = 0; mi < 4; ++mi) {
      #pragma unroll
      for (int ni = 0; ni < 2; ++ni) {   // local cols 0..31 only
        const int nl = ni * 16 + r16;
        const float bv = bc[nl];
        #pragma unroll
        for (int rg = 0; rg < 4; ++rg) {
          const int m = blockIdx.x * 128 + wr * 64 + mi * 16 + quad * 4 + rg;
          outParent[(size_t)m * 32 + nl] = acc[mi][ni][rg] + bv;
        }
      }
    }
  }
}

// per-sample expert slice of dense2 + bias
__global__ __launch_bounds__(128) void k_gather(
    const int* __restrict__ y, const ushort* __restrict__ dense2,
    const float* __restrict__ cb0, const float* __restrict__ cb1,
    float* __restrict__ out0, float* __restrict__ out1)
{
  const int b = blockIdx.x;
  const int t = threadIdx.x;
  const int e = y[b];
  if (t < 32) {
    out0[b * 32 + t] =
        bf16u_to_f32(dense2[(size_t)b * 3072 + e * 32 + t]) + cb0[e * 32 + t];
  } else if (t < 96) {
    const int n = t - 32;
    out1[b * 64 + n] =
        bf16u_to_f32(dense2[(size_t)b * 3072 + 1024 + e * 64 + n]) + cb1[e * 64 + n];
  }
}

// ---------------------------------------------------------------------------

extern "C" void kernel_launch(void* const* d_in, const int* in_sizes, int n_in,
                              void* d_out, int out_size, void* d_ws, size_t ws_size,
                              hipStream_t stream) {
  const float* x   = (const float*)d_in[0];
  const int*   y   = (const int*)  d_in[1];
  const float* Wp  = (const float*)d_in[2];
  const float* bp  = (const float*)d_in[3];
  const float* Ws  = (const float*)d_in[4];
  const float* bs  = (const float*)d_in[5];
  const float* Wc  = (const float*)d_in[6];
  const float* bc  = (const float*)d_in[7];
  const float* cw0 = (const float*)d_in[8];
  const float* cb0 = (const float*)d_in[9];
  const float* cw1 = (const float*)d_in[10];
  const float* cb1 = (const float*)d_in[11];

  float* out = (float*)d_out;
  float* parent_logits = out;               // [4096,32]
  float* child0        = out + 131072;      // [4096,32]
  float* child1        = out + 262144;      // [4096,64]
  float* P             = out + 524288;      // [4096,1024]
  float* S             = out + 4718592;     // [4096,1024]

  char* ws = (char*)d_ws;
  ushort* xb     = (ushort*)(ws);                 // 32 MB (x bf16)
  ushort* dense2 = (ushort*)(ws);                 // aliases xb (dead after gemm1): 24.6 MB
  ushort* Bt1    = (ushort*)(ws + 33554432);      // 16 MB  [2048][4096]
  ushort* Pb     = (ushort*)(ws + 50331648);      // 8 MB   [4096][1024]
  ushort* Sb     = (ushort*)(ws + 58720256);      // 8 MB   [4096][1024]
  ushort* Bt2    = (ushort*)(ws + 67108864);      // 6.25MB [3200][1024]

  k_cast_x     <<<8192, 256, 0, stream>>>(x, xb);
  k_transpose_w<<<dim3(64, 16, 2), 256, 0, stream>>>(Wp, Ws, Bt1);
  k_prep_bt2   <<<3200, 256, 0, stream>>>(cw0, cw1, Wc, Bt2);
  k_gemm1      <<<dim3(32, 16), 256, 0, stream>>>(xb, Bt1, bp, bs, P, S, Pb, Sb);
  k_gemm2      <<<dim3(32, 25), 256, 0, stream>>>(Sb, Pb, Bt2, bc, dense2, parent_logits);
  k_gather     <<<4096, 128, 0, stream>>>(y, dense2, cb0, cb1, child0, child1);
}